// Round 3
// baseline (454.808 us; speedup 1.0000x reference)
//
#include <hip/hip_runtime.h>
#include <hip/hip_bf16.h>
#include <math.h>

// B=4, T=2048, C=1024, H=16, D=64. All dims divide tiles exactly.
typedef __bf16 bf16;
typedef __bf16 bf16x8 __attribute__((ext_vector_type(8)));
typedef __bf16 bf16x4 __attribute__((ext_vector_type(4)));
typedef float  f32x4  __attribute__((ext_vector_type(4)));

// async 16B/lane global->LDS. lds base must be wave-uniform; HW adds lane*16.
__device__ __forceinline__ void gld_lds16(const bf16* g, bf16* l) {
    void* gv = (void*)g;  // drop const
    __builtin_amdgcn_global_load_lds(
        (__attribute__((address_space(1))) void*)gv,
        (__attribute__((address_space(3))) void*)l, 16, 0, 0);
}

// ---------------- fp32 -> bf16 elementwise cast ----------------
__global__ void k_cvt_bf16(const float* __restrict__ in, bf16* __restrict__ out, int n4) {
    int i = blockIdx.x * blockDim.x + threadIdx.x;
    if (i < n4) {
        float4 v = ((const float4*)in)[i];
        bf16x4 o;
        o[0] = (bf16)v.x; o[1] = (bf16)v.y; o[2] = (bf16)v.z; o[3] = (bf16)v.w;
        ((bf16x4*)out)[i] = o;
    }
}

// ---------------- fp32 [R][C] -> bf16 [C][R] transpose+cast ----------------
// grid (C/64, R/64), block 256
__global__ void k_transpose_cvt(const float* __restrict__ in, bf16* __restrict__ out,
                                int R, int C) {
    __shared__ float tile[64][68];
    int c0 = blockIdx.x * 64, r0 = blockIdx.y * 64;
    int tid = threadIdx.x;
#pragma unroll
    for (int i = 0; i < 4; ++i) {            // 1024 float4 chunks
        int chunk = tid + i * 256;
        int r = chunk >> 4, c4 = (chunk & 15) * 4;
        float4 v = *(const float4*)(in + (size_t)(r0 + r) * C + c0 + c4);
        tile[r][c4 + 0] = v.x; tile[r][c4 + 1] = v.y;
        tile[r][c4 + 2] = v.z; tile[r][c4 + 3] = v.w;
    }
    __syncthreads();
#pragma unroll
    for (int i = 0; i < 2; ++i) {            // 512 chunks of 8 bf16
        int chunk = tid + i * 256;
        int c = chunk >> 3, k8 = (chunk & 7) * 8;
        bf16x8 v;
#pragma unroll
        for (int j = 0; j < 8; ++j) v[j] = (bf16)tile[k8 + j][c];
        *(bf16x8*)(out + (size_t)(c0 + c) * R + r0 + k8) = v;
    }
}

// ---------------- V slice of qkv -> vt[(bh*64+d)*2048 + t] ----------------
// grid (T/64, B*H), block 256
__global__ void k_transpose_v(const bf16* __restrict__ qkv, bf16* __restrict__ vt) {
    __shared__ bf16 tile[64][72];
    int bh = blockIdx.y, b = bh >> 4, h = bh & 15;
    int t0 = blockIdx.x * 64;
    int tid = threadIdx.x;
    const bf16* src = qkv + (size_t)(b * 2048 + t0) * 3072 + 2048 + h * 64;
#pragma unroll
    for (int i = 0; i < 2; ++i) {
        int chunk = tid + i * 256;
        int t = chunk >> 3, d8 = (chunk & 7) * 8;
        bf16x8 v = *(const bf16x8*)(src + (size_t)t * 3072 + d8);
#pragma unroll
        for (int j = 0; j < 8; ++j) tile[t][d8 + j] = v[j];
    }
    __syncthreads();
#pragma unroll
    for (int i = 0; i < 2; ++i) {
        int chunk = tid + i * 256;
        int d = chunk >> 3, t8 = (chunk & 7) * 8;
        bf16x8 v;
#pragma unroll
        for (int j = 0; j < 8; ++j) v[j] = tile[t8 + j][d];
        *(bf16x8*)(vt + ((size_t)bh * 64 + d) * 2048 + t0 + t8) = v;
    }
}

// ---------------- GEMM: C[M][N] = A[M][K] * Bt[N][K]^T + bias ----------------
template <bool OUT_BF16>
__global__ __launch_bounds__(256, 2) void k_gemm(
    const bf16* __restrict__ A, const bf16* __restrict__ Bt,
    const float* __restrict__ bias, void* __restrict__ Cout,
    int M, int N, int K) {
    __shared__ __align__(16) bf16 lA[128 * 32];
    __shared__ __align__(16) bf16 lB[128 * 32];
    int tid = threadIdx.x;
    int wid = tid >> 6, lane = tid & 63;
    int quad = lane >> 4, l16 = lane & 15;
    int bm = blockIdx.y * 128, bn = blockIdx.x * 128;
    int wm = (wid >> 1) * 64, wn = (wid & 1) * 64;

    f32x4 zero = {0.f, 0.f, 0.f, 0.f};
    f32x4 acc[4][4];
#pragma unroll
    for (int i = 0; i < 4; ++i)
#pragma unroll
        for (int j = 0; j < 4; ++j) acc[i][j] = zero;

    for (int k0 = 0; k0 < K; k0 += 32) {
        __syncthreads();
#pragma unroll
        for (int i = 0; i < 2; ++i) {
            int chunk = (wid * 2 + i) * 64 + lane;     // 0..511
            int row = chunk >> 2, col = (chunk & 3) * 8;
            gld_lds16(A  + (size_t)(bm + row) * K + k0 + col, lA + (wid * 2 + i) * 512);
            gld_lds16(Bt + (size_t)(bn + row) * K + k0 + col, lB + (wid * 2 + i) * 512);
        }
        __syncthreads();
        bf16x8 af[4], bg[4];
#pragma unroll
        for (int i = 0; i < 4; ++i) {
            af[i] = *(const bf16x8*)(lA + (wm + i * 16 + l16) * 32 + quad * 8);
            bg[i] = *(const bf16x8*)(lB + (wn + i * 16 + l16) * 32 + quad * 8);
        }
#pragma unroll
        for (int i = 0; i < 4; ++i)
#pragma unroll
            for (int j = 0; j < 4; ++j)
                acc[i][j] = __builtin_amdgcn_mfma_f32_16x16x32_bf16(af[i], bg[j], acc[i][j], 0, 0, 0);
    }
#pragma unroll
    for (int i = 0; i < 4; ++i) {
#pragma unroll
        for (int j = 0; j < 4; ++j) {
            int col = bn + wn + j * 16 + l16;
            float bv = bias ? bias[col] : 0.f;
#pragma unroll
            for (int r = 0; r < 4; ++r) {
                int row = bm + wm + i * 16 + quad * 4 + r;
                float v = acc[i][j][r] + bv;
                if (OUT_BF16) ((bf16*)Cout)[(size_t)row * N + col] = (bf16)v;
                else          ((float*)Cout)[(size_t)row * N + col] = v;
            }
        }
    }
}

// ---------------- flash attention (v3: barrier-free, wave-independent) ------
// One wave owns 32 q-rows; iterates over its k-tiles (64 wide) with K/V frags
// loaded DIRECTLY global->VGPR (line-coalesced). No __syncthreads at all.
// LDS only for the per-wave P C-layout->A-layout round trip (rows padded to
// 72 bf16 to kill row aliasing). Softmax shift -10 folded into MFMA acc init.

template <int IN, bool MASK>
__device__ __forceinline__ void attn_tile(
    const bf16* __restrict__ kbase, const bf16* __restrict__ vbase,
    int t0, int q0, int l16, int quad,
    const bf16x8 (&qf)[2][2], bf16* __restrict__ lPw,
    f32x4 (&o)[2][4], float (&lsum)[2][4]) {
    const int CQ = 3072, T = 2048;
    constexpr int KF = IN / 2;          // populated 32-wide k-halves for PV
    f32x4 m10 = {-10.f, -10.f, -10.f, -10.f};
    f32x4 s[2][IN];
#pragma unroll
    for (int qi = 0; qi < 2; ++qi)
#pragma unroll
        for (int in = 0; in < IN; ++in) s[qi][in] = m10;

    // S = (Q/8)K^T - 10 : K B-frags straight from global
#pragma unroll
    for (int kf = 0; kf < 2; ++kf) {
        bf16x8 kb[IN];
#pragma unroll
        for (int in = 0; in < IN; ++in)
            kb[in] = *(const bf16x8*)(kbase + (size_t)(t0 + in * 16 + l16) * CQ + kf * 32 + quad * 8);
#pragma unroll
        for (int qi = 0; qi < 2; ++qi)
#pragma unroll
            for (int in = 0; in < IN; ++in)
                s[qi][in] = __builtin_amdgcn_mfma_f32_16x16x32_bf16(qf[qi][kf], kb[in], s[qi][in], 0, 0, 0);
    }

    // V B-frags issued early; latency hides behind exp + P writes
    bf16x8 vb[KF][4];
#pragma unroll
    for (int kf = 0; kf < KF; ++kf)
#pragma unroll
        for (int dn = 0; dn < 4; ++dn)
            vb[kf][dn] = *(const bf16x8*)(vbase + (size_t)(dn * 16 + l16) * T + t0 + kf * 32 + quad * 8);

    // p = exp(S); optional causal mask; accumulate row sums; write P to LDS
#pragma unroll
    for (int qi = 0; qi < 2; ++qi)
#pragma unroll
        for (int in = 0; in < IN; ++in)
#pragma unroll
            for (int r = 0; r < 4; ++r) {
                float e = __expf(s[qi][in][r]);
                if (MASK) {
                    int col = in * 16 + l16;
                    int row = (q0 - t0) + qi * 16 + quad * 4 + r;
                    if (col > row) e = 0.f;
                }
                lsum[qi][r] += e;
                lPw[(qi * 16 + quad * 4 + r) * 72 + in * 16 + l16] = (bf16)e;
            }

    // P A-frags from LDS (same-wave; lgkmcnt ordering only), O += P V
#pragma unroll
    for (int qi = 0; qi < 2; ++qi)
#pragma unroll
        for (int kf = 0; kf < KF; ++kf) {
            bf16x8 pa = *(const bf16x8*)(lPw + (qi * 16 + l16) * 72 + kf * 32 + quad * 8);
#pragma unroll
            for (int dn = 0; dn < 4; ++dn)
                o[qi][dn] = __builtin_amdgcn_mfma_f32_16x16x32_bf16(pa, vb[kf][dn], o[qi][dn], 0, 0, 0);
        }
}

__global__ __launch_bounds__(256, 4) void k_attn(
    const bf16* __restrict__ qkv,   // [B*T][3072]
    const bf16* __restrict__ vt,    // [(bh*64+d)*2048 + t]
    bf16* __restrict__ y) {         // [B*T][1024]
    __shared__ __align__(16) bf16 lP[4][32 * 72];
    const int T = 2048, CQ = 3072;
    int tid = threadIdx.x, wid = tid >> 6, lane = tid & 63;
    int quad = lane >> 4, l16 = lane & 15;
    // XCD-aware swizzle: each XCD works on 8 bh -> its K/V set (4MB) fits L2.
    int x = blockIdx.x;
    int xcd = x & 7, idx = x >> 3;
    int gw = idx * 4 + wid;              // 0..511 within XCD
    int bh = xcd * 8 + (gw >> 6);        // 0..63
    int rw = 63 - (gw & 63);             // 32-row block, heavy first
    int b = bh >> 4, h = bh & 15;
    int q0 = rw * 32;
    const bf16* qbase = qkv + (size_t)(b * T + q0) * CQ + h * 64;
    const bf16* kbase = qkv + (size_t)(b * T) * CQ + 1024 + h * 64;
    const bf16* vbase = vt + (size_t)bh * 64 * T;
    bf16* lPw = lP[wid];

    // Q A-frags (2 row-halves), prescaled by 1/sqrt(D)=0.125 (exact in bf16)
    bf16x8 qf[2][2];
#pragma unroll
    for (int qi = 0; qi < 2; ++qi)
#pragma unroll
        for (int kf = 0; kf < 2; ++kf) {
            bf16x8 v = *(const bf16x8*)(qbase + (size_t)(qi * 16 + l16) * CQ + kf * 32 + quad * 8);
#pragma unroll
            for (int j = 0; j < 8; ++j) v[j] = (bf16)((float)v[j] * 0.125f);
            qf[qi][kf] = v;
        }

    f32x4 zero = {0.f, 0.f, 0.f, 0.f};
    f32x4 o[2][4];
    float lsum[2][4];
#pragma unroll
    for (int qi = 0; qi < 2; ++qi)
#pragma unroll
        for (int i = 0; i < 4; ++i) { o[qi][i] = zero; lsum[qi][i] = 0.f; }

    int kt0 = q0 >> 6;                    // index of diagonal 64-tile
    for (int kt = 0; kt < kt0; ++kt)
        attn_tile<4, false>(kbase, vbase, kt * 64, q0, l16, quad, qf, lPw, o, lsum);
    if (q0 & 32) attn_tile<4, true>(kbase, vbase, kt0 * 64, q0, l16, quad, qf, lPw, o, lsum);
    else         attn_tile<2, true>(kbase, vbase, kt0 * 64, q0, l16, quad, qf, lPw, o, lsum);

    // epilogue: reduce row sums across the 16 lanes holding each row, then O/l
    float linv[2][4];
#pragma unroll
    for (int qi = 0; qi < 2; ++qi)
#pragma unroll
        for (int r = 0; r < 4; ++r) {
            float l = lsum[qi][r];
#pragma unroll
            for (int mk = 1; mk < 16; mk <<= 1) l += __shfl_xor(l, mk, 64);
            linv[qi][r] = 1.f / l;
        }
#pragma unroll
    for (int qi = 0; qi < 2; ++qi)
#pragma unroll
        for (int dn = 0; dn < 4; ++dn)
#pragma unroll
            for (int r = 0; r < 4; ++r) {
                int row = q0 + qi * 16 + quad * 4 + r;
                float v = o[qi][dn][r] * linv[qi][r];
                y[(size_t)(b * T + row) * 1024 + h * 64 + dn * 16 + l16] = (bf16)v;
            }
}

extern "C" void kernel_launch(void* const* d_in, const int* in_sizes, int n_in,
                              void* d_out, int out_size, void* d_ws, size_t ws_size,
                              hipStream_t stream) {
    const float* x     = (const float*)d_in[0];
    const float* w_qkv = (const float*)d_in[1];
    const float* b_qkv = (const float*)d_in[2];
    const float* w_out = (const float*)d_in[3];
    const float* b_out = (const float*)d_in[4];
    float* out = (float*)d_out;

    const int B = 4, T = 2048, C = 1024, H = 16;
    const int M = B * T;  // 8192

    // workspace layout (88 MB total); vt aliases xb (xb dead after GEMM1)
    char* ws = (char*)d_ws;
    bf16* xb    = (bf16*)(ws);                        // 16 MB
    bf16* wqkvT = (bf16*)(ws + (16ull << 20));        //  6 MB
    bf16* woutT = (bf16*)(ws + (22ull << 20));        //  2 MB
    bf16* qkvb  = (bf16*)(ws + (24ull << 20));        // 48 MB
    bf16* yb    = (bf16*)(ws + (72ull << 20));        // 16 MB
    bf16* vtb   = xb;

    k_cvt_bf16<<<(M * C / 4 + 255) / 256, 256, 0, stream>>>(x, xb, M * C / 4);
    k_transpose_cvt<<<dim3(3 * C / 64, C / 64), 256, 0, stream>>>(w_qkv, wqkvT, C, 3 * C);
    k_transpose_cvt<<<dim3(C / 64, C / 64), 256, 0, stream>>>(w_out, woutT, C, C);
    k_gemm<true><<<dim3(3 * C / 128, M / 128), 256, 0, stream>>>(xb, wqkvT, b_qkv, qkvb, M, 3 * C, C);
    k_transpose_v<<<dim3(T / 64, B * H), 256, 0, stream>>>(qkvb, vtb);
    k_attn<<<dim3(1024, 1), 256, 0, stream>>>(qkvb, vtb, yb);
    k_gemm<false><<<dim3(C / 128, M / 128), 256, 0, stream>>>(yb, woutT, b_out, out, M, C, C);
}

// Round 4
// 301.359 us; speedup vs baseline: 1.5092x; 1.5092x over previous
//
#include <hip/hip_runtime.h>
#include <hip/hip_bf16.h>
#include <math.h>

// B=4, T=2048, C=1024, H=16, D=64. All dims divide tiles exactly.
typedef __bf16 bf16;
typedef __bf16 bf16x8 __attribute__((ext_vector_type(8)));
typedef __bf16 bf16x4 __attribute__((ext_vector_type(4)));
typedef float  f32x4  __attribute__((ext_vector_type(4)));

// async 16B/lane global->LDS. lds base must be wave-uniform; HW adds lane*16.
__device__ __forceinline__ void gld_lds16(const bf16* g, bf16* l) {
    void* gv = (void*)g;  // drop const
    __builtin_amdgcn_global_load_lds(
        (__attribute__((address_space(1))) void*)gv,
        (__attribute__((address_space(3))) void*)l, 16, 0, 0);
}

// ---------------- fp32 -> bf16 elementwise cast ----------------
__global__ void k_cvt_bf16(const float* __restrict__ in, bf16* __restrict__ out, int n4) {
    int i = blockIdx.x * blockDim.x + threadIdx.x;
    if (i < n4) {
        float4 v = ((const float4*)in)[i];
        bf16x4 o;
        o[0] = (bf16)v.x; o[1] = (bf16)v.y; o[2] = (bf16)v.z; o[3] = (bf16)v.w;
        ((bf16x4*)out)[i] = o;
    }
}

// ---------------- fp32 [R][C] -> bf16 [C][R] transpose+cast ----------------
// grid (C/64, R/64), block 256
__global__ void k_transpose_cvt(const float* __restrict__ in, bf16* __restrict__ out,
                                int R, int C) {
    __shared__ float tile[64][68];
    int c0 = blockIdx.x * 64, r0 = blockIdx.y * 64;
    int tid = threadIdx.x;
#pragma unroll
    for (int i = 0; i < 4; ++i) {            // 1024 float4 chunks
        int chunk = tid + i * 256;
        int r = chunk >> 4, c4 = (chunk & 15) * 4;
        float4 v = *(const float4*)(in + (size_t)(r0 + r) * C + c0 + c4);
        tile[r][c4 + 0] = v.x; tile[r][c4 + 1] = v.y;
        tile[r][c4 + 2] = v.z; tile[r][c4 + 3] = v.w;
    }
    __syncthreads();
#pragma unroll
    for (int i = 0; i < 2; ++i) {            // 512 chunks of 8 bf16
        int chunk = tid + i * 256;
        int c = chunk >> 3, k8 = (chunk & 7) * 8;
        bf16x8 v;
#pragma unroll
        for (int j = 0; j < 8; ++j) v[j] = (bf16)tile[k8 + j][c];
        *(bf16x8*)(out + (size_t)(c0 + c) * R + r0 + k8) = v;
    }
}

// ---------------- V slice of qkv -> vt[(bh*64+d)*2048 + t] ----------------
// grid (T/64, B*H), block 256
__global__ void k_transpose_v(const bf16* __restrict__ qkv, bf16* __restrict__ vt) {
    __shared__ bf16 tile[64][72];
    int bh = blockIdx.y, b = bh >> 4, h = bh & 15;
    int t0 = blockIdx.x * 64;
    int tid = threadIdx.x;
    const bf16* src = qkv + (size_t)(b * 2048 + t0) * 3072 + 2048 + h * 64;
#pragma unroll
    for (int i = 0; i < 2; ++i) {
        int chunk = tid + i * 256;
        int t = chunk >> 3, d8 = (chunk & 7) * 8;
        bf16x8 v = *(const bf16x8*)(src + (size_t)t * 3072 + d8);
#pragma unroll
        for (int j = 0; j < 8; ++j) tile[t][d8 + j] = v[j];
    }
    __syncthreads();
#pragma unroll
    for (int i = 0; i < 2; ++i) {
        int chunk = tid + i * 256;
        int d = chunk >> 3, t8 = (chunk & 7) * 8;
        bf16x8 v;
#pragma unroll
        for (int j = 0; j < 8; ++j) v[j] = tile[t8 + j][d];
        *(bf16x8*)(vt + ((size_t)bh * 64 + d) * 2048 + t0 + t8) = v;
    }
}

// ---------------- GEMM: C[M][N] = A[M][K] * Bt[N][K]^T + bias ----------------
template <bool OUT_BF16>
__global__ __launch_bounds__(256, 2) void k_gemm(
    const bf16* __restrict__ A, const bf16* __restrict__ Bt,
    const float* __restrict__ bias, void* __restrict__ Cout,
    int M, int N, int K) {
    __shared__ __align__(16) bf16 lA[128 * 32];
    __shared__ __align__(16) bf16 lB[128 * 32];
    int tid = threadIdx.x;
    int wid = tid >> 6, lane = tid & 63;
    int quad = lane >> 4, l16 = lane & 15;
    int bm = blockIdx.y * 128, bn = blockIdx.x * 128;
    int wm = (wid >> 1) * 64, wn = (wid & 1) * 64;

    f32x4 zero = {0.f, 0.f, 0.f, 0.f};
    f32x4 acc[4][4];
#pragma unroll
    for (int i = 0; i < 4; ++i)
#pragma unroll
        for (int j = 0; j < 4; ++j) acc[i][j] = zero;

    for (int k0 = 0; k0 < K; k0 += 32) {
        __syncthreads();
#pragma unroll
        for (int i = 0; i < 2; ++i) {
            int chunk = (wid * 2 + i) * 64 + lane;     // 0..511
            int row = chunk >> 2, col = (chunk & 3) * 8;
            gld_lds16(A  + (size_t)(bm + row) * K + k0 + col, lA + (wid * 2 + i) * 512);
            gld_lds16(Bt + (size_t)(bn + row) * K + k0 + col, lB + (wid * 2 + i) * 512);
        }
        __syncthreads();
        bf16x8 af[4], bg[4];
#pragma unroll
        for (int i = 0; i < 4; ++i) {
            af[i] = *(const bf16x8*)(lA + (wm + i * 16 + l16) * 32 + quad * 8);
            bg[i] = *(const bf16x8*)(lB + (wn + i * 16 + l16) * 32 + quad * 8);
        }
#pragma unroll
        for (int i = 0; i < 4; ++i)
#pragma unroll
            for (int j = 0; j < 4; ++j)
                acc[i][j] = __builtin_amdgcn_mfma_f32_16x16x32_bf16(af[i], bg[j], acc[i][j], 0, 0, 0);
    }
#pragma unroll
    for (int i = 0; i < 4; ++i) {
#pragma unroll
        for (int j = 0; j < 4; ++j) {
            int col = bn + wn + j * 16 + l16;
            float bv = bias ? bias[col] : 0.f;
#pragma unroll
            for (int r = 0; r < 4; ++r) {
                int row = bm + wm + i * 16 + quad * 4 + r;
                float v = acc[i][j][r] + bv;
                if (OUT_BF16) ((bf16*)Cout)[(size_t)row * N + col] = (bf16)v;
                else          ((float*)Cout)[(size_t)row * N + col] = v;
            }
        }
    }
}

// ---------------- flash attention (v4) ----------------
// Block = 128 q-rows, 4 waves x 32 rows (2 sub-tiles of 16). K/V tiles (64
// wide) double-buffered in LDS, kf-split [2][64][32] (bank-uniform), one
// barrier per k-tile. P per-wave 32x72 (stride 72 kills write conflicts;
// b128 reads land uniform). Softmax shift -10 folded into MFMA acc init.
__global__ __launch_bounds__(256, 3) void k_attn(
    const bf16* __restrict__ qkv,   // [B*T][3072]
    const bf16* __restrict__ vt,    // [(bh*64+d)*2048 + t]
    bf16* __restrict__ y) {         // [B*T][1024]
    __shared__ __align__(16) bf16 lK[2][4096];
    __shared__ __align__(16) bf16 lV[2][4096];
    __shared__ __align__(16) bf16 lP[4][32 * 72];

    const int T = 2048, CQ = 3072;
    int tid = threadIdx.x, wid = tid >> 6, lane = tid & 63;
    int quad = lane >> 4, l16 = lane & 15;
    // bh spread so each XCD's 8 bh (4MB K+V) fits its L2; heavy qb first.
    int x = blockIdx.x;
    int bh = ((x & 7) << 3) | ((x >> 3) & 7);
    int qb = 15 - (x >> 6);                    // 128-row block index, 0..15
    int b = bh >> 4, h = bh & 15;
    int q0 = qb * 128;
    int rb = qb * 4 + wid;                     // this wave's 32-row block idx
    int mdiag = rb >> 1;                       // k-tile containing diagonal
    int ntiles = qb * 2 + 2;                   // tiles staged by this block

    const bf16* qbase = qkv + (size_t)(b * T + q0 + wid * 32) * CQ + h * 64;
    const bf16* kbase = qkv + (size_t)(b * T) * CQ + 1024 + h * 64;
    const bf16* vbase = vt + (size_t)bh * 64 * T;
    bf16* lPw = lP[wid];

    // stage K/V tile kt into buffer buf: [kf][64][32], linear chunk mapping
    auto stage = [&](int kt, int buf) {
        int t0 = kt * 64;
#pragma unroll
        for (int i = 0; i < 2; ++i) {
            int j = (wid * 2 + i) * 64 + lane;         // 0..511
            int kf = j >> 8, r = (j & 255) >> 2, c8 = (j & 3) * 8;
            gld_lds16(kbase + (size_t)(t0 + r) * CQ + kf * 32 + c8, &lK[buf][(wid * 2 + i) * 512]);
            gld_lds16(vbase + (size_t)r * T + t0 + kf * 32 + c8,    &lV[buf][(wid * 2 + i) * 512]);
        }
    };

    // Q A-frags (2 row-halves of this wave's 32 rows), prescaled by 0.125
    bf16x8 qf[2][2];
#pragma unroll
    for (int qi = 0; qi < 2; ++qi)
#pragma unroll
        for (int kf = 0; kf < 2; ++kf) {
            bf16x8 v = *(const bf16x8*)(qbase + (size_t)(qi * 16 + l16) * CQ + kf * 32 + quad * 8);
#pragma unroll
            for (int j = 0; j < 8; ++j) v[j] = (bf16)((float)v[j] * 0.125f);
            qf[qi][kf] = v;
        }

    f32x4 zero = {0.f, 0.f, 0.f, 0.f};
    f32x4 m10 = {-10.f, -10.f, -10.f, -10.f};
    f32x4 o[2][4];
    float lsum[2][4];
#pragma unroll
    for (int qi = 0; qi < 2; ++qi)
#pragma unroll
        for (int i = 0; i < 4; ++i) { o[qi][i] = zero; lsum[qi][i] = 0.f; }

    stage(0, 0);
    for (int kt = 0; kt < ntiles; ++kt) {
        __syncthreads();                       // buf[kt&1] ready (vmcnt drained)
        if (kt + 1 < ntiles) stage(kt + 1, (kt + 1) & 1);
        if (kt > mdiag) continue;              // no live cols; still hit barriers
        const bf16* Kb = lK[kt & 1];
        const bf16* Vb = lV[kt & 1];
        bool diag = (kt == mdiag);
        bool half = diag && !(rb & 1);         // even rb: only cols 0..31 live

        // S = (Q/8)K^T - 10
        f32x4 s[2][4];
#pragma unroll
        for (int qi = 0; qi < 2; ++qi)
#pragma unroll
            for (int in = 0; in < 4; ++in) s[qi][in] = m10;
        int in_hi = half ? 2 : 4;
        for (int kf = 0; kf < 2; ++kf)
            for (int in = 0; in < in_hi; ++in) {
                bf16x8 kb = *(const bf16x8*)(Kb + kf * 2048 + (in * 16 + l16) * 32 + quad * 8);
#pragma unroll
                for (int qi = 0; qi < 2; ++qi)
                    s[qi][in] = __builtin_amdgcn_mfma_f32_16x16x32_bf16(qf[qi][kf], kb, s[qi][in], 0, 0, 0);
            }

        // V B-frags issued early; latency hides behind exp + P writes
        bf16x8 vb[2][4];
#pragma unroll
        for (int kf = 0; kf < 2; ++kf)
#pragma unroll
            for (int dn = 0; dn < 4; ++dn)
                vb[kf][dn] = *(const bf16x8*)(Vb + kf * 2048 + (dn * 16 + l16) * 32 + quad * 8);

        // p = exp(S); causal mask on diag; row-sum partials; P -> LDS
        int rl0 = (rb * 32) - kt * 64;         // row-local offset vs tile cols
        for (int qi = 0; qi < 2; ++qi)
#pragma unroll
            for (int in = 0; in < 4; ++in) {
                if (in >= in_hi) {             // dead cols on half-diag tile
#pragma unroll
                    for (int r = 0; r < 4; ++r)
                        lPw[(qi * 16 + quad * 4 + r) * 72 + in * 16 + l16] = (bf16)0.f;
                    continue;
                }
#pragma unroll
                for (int r = 0; r < 4; ++r) {
                    float e = __expf(s[qi][in][r]);
                    if (diag) {
                        int col = in * 16 + l16;
                        int row = rl0 + qi * 16 + quad * 4 + r;
                        if (col > row) e = 0.f;
                    }
                    lsum[qi][r] += e;
                    lPw[(qi * 16 + quad * 4 + r) * 72 + in * 16 + l16] = (bf16)e;
                }
            }

        // P A-frags (same-wave LDS; lgkmcnt only), O += P V
#pragma unroll
        for (int qi = 0; qi < 2; ++qi)
#pragma unroll
            for (int kf = 0; kf < 2; ++kf) {
                bf16x8 pa = *(const bf16x8*)(lPw + (qi * 16 + l16) * 72 + kf * 32 + quad * 8);
#pragma unroll
                for (int dn = 0; dn < 4; ++dn)
                    o[qi][dn] = __builtin_amdgcn_mfma_f32_16x16x32_bf16(pa, vb[kf][dn], o[qi][dn], 0, 0, 0);
            }
    }

    // epilogue: reduce row sums across the 16 lanes holding each row, then O/l
    float linv[2][4];
#pragma unroll
    for (int qi = 0; qi < 2; ++qi)
#pragma unroll
        for (int r = 0; r < 4; ++r) {
            float l = lsum[qi][r];
#pragma unroll
            for (int mk = 1; mk < 16; mk <<= 1) l += __shfl_xor(l, mk, 64);
            linv[qi][r] = 1.f / l;
        }
#pragma unroll
    for (int qi = 0; qi < 2; ++qi)
#pragma unroll
        for (int dn = 0; dn < 4; ++dn)
#pragma unroll
            for (int r = 0; r < 4; ++r) {
                int row = q0 + wid * 32 + qi * 16 + quad * 4 + r;
                float v = o[qi][dn][r] * linv[qi][r];
                y[(size_t)(b * T + row) * 1024 + h * 64 + dn * 16 + l16] = (bf16)v;
            }
}

extern "C" void kernel_launch(void* const* d_in, const int* in_sizes, int n_in,
                              void* d_out, int out_size, void* d_ws, size_t ws_size,
                              hipStream_t stream) {
    const float* x     = (const float*)d_in[0];
    const float* w_qkv = (const float*)d_in[1];
    const float* b_qkv = (const float*)d_in[2];
    const float* w_out = (const float*)d_in[3];
    const float* b_out = (const float*)d_in[4];
    float* out = (float*)d_out;

    const int B = 4, T = 2048, C = 1024, H = 16;
    const int M = B * T;  // 8192

    // workspace layout (88 MB total); vt aliases xb (xb dead after GEMM1)
    char* ws = (char*)d_ws;
    bf16* xb    = (bf16*)(ws);                        // 16 MB
    bf16* wqkvT = (bf16*)(ws + (16ull << 20));        //  6 MB
    bf16* woutT = (bf16*)(ws + (22ull << 20));        //  2 MB
    bf16* qkvb  = (bf16*)(ws + (24ull << 20));        // 48 MB
    bf16* yb    = (bf16*)(ws + (72ull << 20));        // 16 MB
    bf16* vtb   = xb;

    k_cvt_bf16<<<(M * C / 4 + 255) / 256, 256, 0, stream>>>(x, xb, M * C / 4);
    k_transpose_cvt<<<dim3(3 * C / 64, C / 64), 256, 0, stream>>>(w_qkv, wqkvT, C, 3 * C);
    k_transpose_cvt<<<dim3(C / 64, C / 64), 256, 0, stream>>>(w_out, woutT, C, C);
    k_gemm<true><<<dim3(3 * C / 128, M / 128), 256, 0, stream>>>(xb, wqkvT, b_qkv, qkvb, M, 3 * C, C);
    k_transpose_v<<<dim3(T / 64, B * H), 256, 0, stream>>>(qkvb, vtb);
    k_attn<<<dim3(1024, 1), 256, 0, stream>>>(qkvb, vtb, yb);
    k_gemm<false><<<dim3(C / 128, M / 128), 256, 0, stream>>>(yb, woutT, b_out, out, M, C, C);
}

// Round 5
// 281.068 us; speedup vs baseline: 1.6181x; 1.0722x over previous
//
#include <hip/hip_runtime.h>
#include <hip/hip_bf16.h>
#include <math.h>

// B=4, T=2048, C=1024, H=16, D=64. All dims divide tiles exactly.
typedef __bf16 bf16;
typedef __bf16 bf16x8 __attribute__((ext_vector_type(8)));
typedef __bf16 bf16x4 __attribute__((ext_vector_type(4)));
typedef float  f32x4  __attribute__((ext_vector_type(4)));

// async 16B/lane global->LDS. lds base must be wave-uniform; HW adds lane*16.
__device__ __forceinline__ void gld_lds16(const bf16* g, bf16* l) {
    void* gv = (void*)g;  // drop const
    __builtin_amdgcn_global_load_lds(
        (__attribute__((address_space(1))) void*)gv,
        (__attribute__((address_space(3))) void*)l, 16, 0, 0);
}

// ---------------- fp32 -> bf16 elementwise cast ----------------
__global__ void k_cvt_bf16(const float* __restrict__ in, bf16* __restrict__ out, int n4) {
    int i = blockIdx.x * blockDim.x + threadIdx.x;
    if (i < n4) {
        float4 v = ((const float4*)in)[i];
        bf16x4 o;
        o[0] = (bf16)v.x; o[1] = (bf16)v.y; o[2] = (bf16)v.z; o[3] = (bf16)v.w;
        ((bf16x4*)out)[i] = o;
    }
}

// ---------------- fp32 [R][C] -> bf16 [C][R] transpose+cast ----------------
// grid (C/64, R/64), block 256
__global__ void k_transpose_cvt(const float* __restrict__ in, bf16* __restrict__ out,
                                int R, int C) {
    __shared__ float tile[64][68];
    int c0 = blockIdx.x * 64, r0 = blockIdx.y * 64;
    int tid = threadIdx.x;
#pragma unroll
    for (int i = 0; i < 4; ++i) {            // 1024 float4 chunks
        int chunk = tid + i * 256;
        int r = chunk >> 4, c4 = (chunk & 15) * 4;
        float4 v = *(const float4*)(in + (size_t)(r0 + r) * C + c0 + c4);
        tile[r][c4 + 0] = v.x; tile[r][c4 + 1] = v.y;
        tile[r][c4 + 2] = v.z; tile[r][c4 + 3] = v.w;
    }
    __syncthreads();
#pragma unroll
    for (int i = 0; i < 2; ++i) {            // 512 chunks of 8 bf16
        int chunk = tid + i * 256;
        int c = chunk >> 3, k8 = (chunk & 7) * 8;
        bf16x8 v;
#pragma unroll
        for (int j = 0; j < 8; ++j) v[j] = (bf16)tile[k8 + j][c];
        *(bf16x8*)(out + (size_t)(c0 + c) * R + r0 + k8) = v;
    }
}

// ---------------- V slice of qkv -> vt[(bh*64+d)*2048 + t] ----------------
// grid (T/64, B*H), block 256
__global__ void k_transpose_v(const bf16* __restrict__ qkv, bf16* __restrict__ vt) {
    __shared__ bf16 tile[64][72];
    int bh = blockIdx.y, b = bh >> 4, h = bh & 15;
    int t0 = blockIdx.x * 64;
    int tid = threadIdx.x;
    const bf16* src = qkv + (size_t)(b * 2048 + t0) * 3072 + 2048 + h * 64;
#pragma unroll
    for (int i = 0; i < 2; ++i) {
        int chunk = tid + i * 256;
        int t = chunk >> 3, d8 = (chunk & 7) * 8;
        bf16x8 v = *(const bf16x8*)(src + (size_t)t * 3072 + d8);
#pragma unroll
        for (int j = 0; j < 8; ++j) tile[t][d8 + j] = v[j];
    }
    __syncthreads();
#pragma unroll
    for (int i = 0; i < 2; ++i) {
        int chunk = tid + i * 256;
        int d = chunk >> 3, t8 = (chunk & 7) * 8;
        bf16x8 v;
#pragma unroll
        for (int j = 0; j < 8; ++j) v[j] = tile[t8 + j][d];
        *(bf16x8*)(vt + ((size_t)bh * 64 + d) * 2048 + t0 + t8) = v;
    }
}

// ---------------- GEMM: C[M][N] = A[M][K] * Bt[N][K]^T + bias ----------------
// 128x128 block tile, 4 waves (2x2) of 64x64, BK=64 kf-split LDS [2][128][32]
// (bank-uniform), global_load_lds width=16 staging, mfma 16x16x32 bf16.
template <bool OUT_BF16>
__global__ __launch_bounds__(256, 2) void k_gemm(
    const bf16* __restrict__ A, const bf16* __restrict__ Bt,
    const float* __restrict__ bias, void* __restrict__ Cout,
    int M, int N, int K) {
    __shared__ __align__(16) bf16 lA[2][4096];
    __shared__ __align__(16) bf16 lB[2][4096];
    int tid = threadIdx.x;
    int wid = tid >> 6, lane = tid & 63;
    int quad = lane >> 4, l16 = lane & 15;
    int bm = blockIdx.y * 128, bn = blockIdx.x * 128;
    int wm = (wid >> 1) * 64, wn = (wid & 1) * 64;

    f32x4 zero = {0.f, 0.f, 0.f, 0.f};
    f32x4 acc[4][4];
#pragma unroll
    for (int i = 0; i < 4; ++i)
#pragma unroll
        for (int j = 0; j < 4; ++j) acc[i][j] = zero;

    for (int k0 = 0; k0 < K; k0 += 64) {
        __syncthreads();
#pragma unroll
        for (int i = 0; i < 4; ++i) {
            int j = (wid * 4 + i) * 64 + lane;          // 0..1023
            int kf = j >> 9, row = (j & 511) >> 2, c8 = (j & 3) * 8;
            gld_lds16(A  + (size_t)(bm + row) * K + k0 + kf * 32 + c8, &lA[0][0] + (wid * 4 + i) * 512);
            gld_lds16(Bt + (size_t)(bn + row) * K + k0 + kf * 32 + c8, &lB[0][0] + (wid * 4 + i) * 512);
        }
        __syncthreads();
#pragma unroll
        for (int kk = 0; kk < 2; ++kk) {
            bf16x8 af[4], bg[4];
#pragma unroll
            for (int i = 0; i < 4; ++i) {
                af[i] = *(const bf16x8*)(&lA[kk][(wm + i * 16 + l16) * 32 + quad * 8]);
                bg[i] = *(const bf16x8*)(&lB[kk][(wn + i * 16 + l16) * 32 + quad * 8]);
            }
#pragma unroll
            for (int i = 0; i < 4; ++i)
#pragma unroll
                for (int j = 0; j < 4; ++j)
                    acc[i][j] = __builtin_amdgcn_mfma_f32_16x16x32_bf16(af[i], bg[j], acc[i][j], 0, 0, 0);
        }
    }
#pragma unroll
    for (int i = 0; i < 4; ++i) {
#pragma unroll
        for (int j = 0; j < 4; ++j) {
            int col = bn + wn + j * 16 + l16;
            float bv = bias ? bias[col] : 0.f;
#pragma unroll
            for (int r = 0; r < 4; ++r) {
                int row = bm + wm + i * 16 + quad * 4 + r;
                float v = acc[i][j][r] + bv;
                if (OUT_BF16) ((bf16*)Cout)[(size_t)row * N + col] = (bf16)v;
                else          ((float*)Cout)[(size_t)row * N + col] = v;
            }
        }
    }
}

// ---------------- flash attention (v5: S^T trick) ----------------
// Block = 128 q-rows, 4 waves x 32 rows. K/V double-buffered kf-split LDS.
// S computed TRANSPOSED (mfma(K,Q)): lane holds fixed q (=l16), 4 consecutive
// t values -> P written as packed ds_write_b64 (bank-perfect), read back as
// b128 A-frags for PV. lsum is a per-lane scalar (t-partials), reduced over
// quads once at the end. Softmax shift -10 folded into MFMA acc init.
__global__ __launch_bounds__(256, 3) void k_attn(
    const bf16* __restrict__ qkv,   // [B*T][3072]
    const bf16* __restrict__ vt,    // [(bh*64+d)*2048 + t]
    bf16* __restrict__ y) {         // [B*T][1024]
    __shared__ __align__(16) bf16 lK[2][4096];
    __shared__ __align__(16) bf16 lV[2][4096];
    __shared__ __align__(16) bf16 lP[4][32 * 72];   // [q 32][t 64+8 pad]

    const int T = 2048, CQ = 3072;
    int tid = threadIdx.x, wid = tid >> 6, lane = tid & 63;
    int quad = lane >> 4, l16 = lane & 15;
    // bh spread so each XCD's 8 bh (4MB K+V) fits its L2; heavy qb first.
    int x = blockIdx.x;
    int bh = ((x & 7) << 3) | ((x >> 3) & 7);
    int qb = 15 - (x >> 6);                    // 128-row block index, 0..15
    int b = bh >> 4, h = bh & 15;
    int q0 = qb * 128;
    int rb = qb * 4 + wid;                     // this wave's 32-row block idx
    int mdiag = rb >> 1;                       // k-tile containing diagonal
    int ntiles = qb * 2 + 2;                   // tiles staged by this block

    const bf16* qbase = qkv + (size_t)(b * T + q0 + wid * 32) * CQ + h * 64;
    const bf16* kbase = qkv + (size_t)(b * T) * CQ + 1024 + h * 64;
    const bf16* vbase = vt + (size_t)bh * 64 * T;
    bf16* lPw = lP[wid];

    // stage K/V tile kt into buffer buf: [kf][64][32], linear chunk mapping
    auto stage = [&](int kt, int buf) {
        int t0 = kt * 64;
#pragma unroll
        for (int i = 0; i < 2; ++i) {
            int j = (wid * 2 + i) * 64 + lane;         // 0..511
            int kf = j >> 8, r = (j & 255) >> 2, c8 = (j & 3) * 8;
            gld_lds16(kbase + (size_t)(t0 + r) * CQ + kf * 32 + c8, &lK[buf][(wid * 2 + i) * 512]);
            gld_lds16(vbase + (size_t)r * T + t0 + kf * 32 + c8,    &lV[buf][(wid * 2 + i) * 512]);
        }
    };

    // Q B-frags (2 row-halves of this wave's 32 rows), prescaled by 0.125
    bf16x8 qf[2][2];
#pragma unroll
    for (int qi = 0; qi < 2; ++qi)
#pragma unroll
        for (int kf = 0; kf < 2; ++kf) {
            bf16x8 v = *(const bf16x8*)(qbase + (size_t)(qi * 16 + l16) * CQ + kf * 32 + quad * 8);
#pragma unroll
            for (int j = 0; j < 8; ++j) v[j] = (bf16)((float)v[j] * 0.125f);
            qf[qi][kf] = v;
        }

    f32x4 zero = {0.f, 0.f, 0.f, 0.f};
    f32x4 m10 = {-10.f, -10.f, -10.f, -10.f};
    f32x4 o[2][4];
    float lsum[2] = {0.f, 0.f};
#pragma unroll
    for (int qi = 0; qi < 2; ++qi)
#pragma unroll
        for (int i = 0; i < 4; ++i) o[qi][i] = zero;

    stage(0, 0);
    for (int kt = 0; kt < ntiles; ++kt) {
        __syncthreads();                       // buf[kt&1] ready (vmcnt drained)
        if (kt + 1 < ntiles) stage(kt + 1, (kt + 1) & 1);
        if (kt > mdiag) continue;              // no live cols; still hit barriers
        const bf16* Kb = lK[kt & 1];
        const bf16* Vb = lV[kt & 1];
        bool diag = (kt == mdiag);
        bool half = diag && !(rb & 1);         // even rb: only t 0..31 live
        int in_hi = half ? 2 : 4;

        // S^T = K (Q/8)^T - 10 : lane holds q=l16, t = in*16+quad*4+r
        f32x4 s[2][4];
#pragma unroll
        for (int qi = 0; qi < 2; ++qi)
#pragma unroll
            for (int in = 0; in < 4; ++in) s[qi][in] = m10;
        for (int kf = 0; kf < 2; ++kf)
            for (int in = 0; in < in_hi; ++in) {
                bf16x8 kb = *(const bf16x8*)(Kb + kf * 2048 + (in * 16 + l16) * 32 + quad * 8);
#pragma unroll
                for (int qi = 0; qi < 2; ++qi)
                    s[qi][in] = __builtin_amdgcn_mfma_f32_16x16x32_bf16(kb, qf[qi][kf], s[qi][in], 0, 0, 0);
            }

        // V B-frags issued early; latency hides behind exp + P writes
        bf16x8 vb[2][4];
#pragma unroll
        for (int kf = 0; kf < 2; ++kf)
#pragma unroll
            for (int dn = 0; dn < 4; ++dn)
                vb[kf][dn] = *(const bf16x8*)(Vb + kf * 2048 + (dn * 16 + l16) * 32 + quad * 8);

        // p = exp(S); causal mask on diag; lane-local t-partial sums;
        // P -> LDS as packed b64 (4 consecutive t per lane)
        int rl0 = (rb * 32) - kt * 64;         // q offset rel to tile t-base
        for (int qi = 0; qi < 2; ++qi) {
            int qloc = rl0 + qi * 16 + l16;
#pragma unroll
            for (int in = 0; in < 4; ++in) {
                bf16x4 pk4;
                if (in >= in_hi) {
                    pk4[0] = pk4[1] = pk4[2] = pk4[3] = (bf16)0.f;
                } else {
#pragma unroll
                    for (int r = 0; r < 4; ++r) {
                        float e = __expf(s[qi][in][r]);
                        if (diag) {
                            int tloc = in * 16 + quad * 4 + r;
                            if (tloc > qloc) e = 0.f;
                        }
                        lsum[qi] += e;
                        pk4[r] = (bf16)e;
                    }
                }
                *(bf16x4*)(lPw + (qi * 16 + l16) * 72 + in * 16 + quad * 4) = pk4;
            }
        }

        // P A-frags (same-wave LDS; lgkmcnt only), O += P V
#pragma unroll
        for (int qi = 0; qi < 2; ++qi)
#pragma unroll
            for (int kf = 0; kf < 2; ++kf) {
                bf16x8 pa = *(const bf16x8*)(lPw + (qi * 16 + l16) * 72 + kf * 32 + quad * 8);
#pragma unroll
                for (int dn = 0; dn < 4; ++dn)
                    o[qi][dn] = __builtin_amdgcn_mfma_f32_16x16x32_bf16(pa, vb[kf][dn], o[qi][dn], 0, 0, 0);
            }
    }

    // epilogue: lsum[qi] is lane-partial over t; rows q=l16 live in all 4
    // quads -> reduce with xor 16/32, then broadcast to C-layout rows.
    float linv[2];
#pragma unroll
    for (int qi = 0; qi < 2; ++qi) {
        float l = lsum[qi];
        l += __shfl_xor(l, 16, 64);
        l += __shfl_xor(l, 32, 64);
        linv[qi] = 1.f / l;
    }
#pragma unroll
    for (int qi = 0; qi < 2; ++qi)
#pragma unroll
        for (int r = 0; r < 4; ++r) {
            float li = __shfl(linv[qi], quad * 4 + r, 64);  // linv for q=quad*4+r
            int row = q0 + wid * 32 + qi * 16 + quad * 4 + r;
#pragma unroll
            for (int dn = 0; dn < 4; ++dn) {
                float v = o[qi][dn][r] * li;
                y[(size_t)(b * T + row) * 1024 + h * 64 + dn * 16 + l16] = (bf16)v;
            }
        }
}

extern "C" void kernel_launch(void* const* d_in, const int* in_sizes, int n_in,
                              void* d_out, int out_size, void* d_ws, size_t ws_size,
                              hipStream_t stream) {
    const float* x     = (const float*)d_in[0];
    const float* w_qkv = (const float*)d_in[1];
    const float* b_qkv = (const float*)d_in[2];
    const float* w_out = (const float*)d_in[3];
    const float* b_out = (const float*)d_in[4];
    float* out = (float*)d_out;

    const int B = 4, T = 2048, C = 1024, H = 16;
    const int M = B * T;  // 8192

    // workspace layout (88 MB total); vt aliases xb (xb dead after GEMM1)
    char* ws = (char*)d_ws;
    bf16* xb    = (bf16*)(ws);                        // 16 MB
    bf16* wqkvT = (bf16*)(ws + (16ull << 20));        //  6 MB
    bf16* woutT = (bf16*)(ws + (22ull << 20));        //  2 MB
    bf16* qkvb  = (bf16*)(ws + (24ull << 20));        // 48 MB
    bf16* yb    = (bf16*)(ws + (72ull << 20));        // 16 MB
    bf16* vtb   = xb;

    k_cvt_bf16<<<(M * C / 4 + 255) / 256, 256, 0, stream>>>(x, xb, M * C / 4);
    k_transpose_cvt<<<dim3(3 * C / 64, C / 64), 256, 0, stream>>>(w_qkv, wqkvT, C, 3 * C);
    k_transpose_cvt<<<dim3(C / 64, C / 64), 256, 0, stream>>>(w_out, woutT, C, C);
    k_gemm<true><<<dim3(3 * C / 128, M / 128), 256, 0, stream>>>(xb, wqkvT, b_qkv, qkvb, M, 3 * C, C);
    k_transpose_v<<<dim3(T / 64, B * H), 256, 0, stream>>>(qkvb, vtb);
    k_attn<<<dim3(1024, 1), 256, 0, stream>>>(qkvb, vtb, yb);
    k_gemm<false><<<dim3(C / 128, M / 128), 256, 0, stream>>>(yb, woutT, b_out, out, M, C, C);
}